// Round 8
// baseline (302.470 us; speedup 1.0000x reference)
//
#include <hip/hip_runtime.h>
#include <hip/hip_bf16.h>

typedef unsigned short u16;
typedef unsigned int   u32;
typedef __attribute__((ext_vector_type(8))) short bf16x8;
typedef __attribute__((ext_vector_type(4))) float f32x4;

#define NB     8192
#define GRID_P 512            // 2 blocks/CU * 256 CU
#define ITERS  (NB / GRID_P)  // 16

__device__ __forceinline__ u32 pack2bf(float a, float b) {
    __hip_bfloat162 h = __float22bfloat162_rn(make_float2(a, b));  // v_cvt_pk_bf16_f32
    return *reinterpret_cast<u32*>(&h);
}

__device__ __forceinline__ u16 f2bf(float x) {
    u32 u = __float_as_uint(x);
    u32 r = u + 0x7FFFu + ((u >> 16) & 1u);
    return (u16)(r >> 16);
}

// Fragment-linear weight layouts (R7, proven): frag f = 512 elems in lane*8 order.
//   w1fr: f = (wv*4 + mt)*4 + ks    elem(l,j): W1[d][c], d=32ks+8*(l>>4)+j, c=64wv+16mt+(l&15)
//   w2fr: f = (wv*4 + et)*8 + ks    elem(l,j): W2[c][e], c=32ks+8*(l>>4)+j, e=64wv+16et+(l&15)
__global__ __launch_bounds__(256) void prep_weights(
    const float* __restrict__ W1, const float* __restrict__ W2,
    u16* __restrict__ w1fr, u16* __restrict__ w2fr)
{
    int tid = blockIdx.x * 256 + threadIdx.x;
    if (tid < 32768) {
        const int f = tid >> 9, r = tid & 511, l = r >> 3, j = r & 7;
        const int wv = f >> 4, mt = (f >> 2) & 3, ks = f & 3;
        const int c = 64 * wv + 16 * mt + (l & 15);
        const int d = 32 * ks + 8 * (l >> 4) + j;
        w1fr[tid] = f2bf(W1[d * 256 + c]);
    } else {
        const int t2 = tid - 32768;
        if (t2 < 65536) {
            const int f = t2 >> 9, r = t2 & 511, l = r >> 3, j = r & 7;
            const int wv = f >> 5, et = (f >> 3) & 3, ks = f & 7;
            const int e = 64 * wv + 16 * et + (l & 15);
            const int c = 32 * ks + 8 * (l >> 4) + j;
            w2fr[t2] = f2bf(W2[c * 256 + e]);
        }
    }
}

// Persistent pipelined: 512 blocks, 16 batches each. Per iteration:
//   L1(xs=b) | B1 sync | glds(b+512 -> xs, fire&forget) | ep1 -> h1s |
//   B2 raw(lgkm only: glds stays in flight) | L2+L3 -> partl |
//   B3 raw(lgkm) | out(b) | B4 sync(vmcnt0: xs[b+512] landed)
// Hazards: xs R->W spans B1; xs W->R spans B4(vmcnt0+barrier). h1s W->R spans B2;
// h1s R->W spans B3+B4+B1. partl W->R spans B3; R->W spans B4+B1+B2.
__global__ __launch_bounds__(256, 2) void fused_mlp(
    const float* __restrict__ X,
    const float* __restrict__ b1, const float* __restrict__ b2,
    const float* __restrict__ W3, const float* __restrict__ b3,
    const u16* __restrict__ w1fr, const u16* __restrict__ w2fr,
    float* __restrict__ out)
{
    __shared__ __align__(16) float xs[64 * 128];   // fp32 X [d=128][n=64], col d-swizzled (R6)
    __shared__ __align__(16) u16   h1s[64 * 256];  // bf16 h1[n][c], 16B-chunk XOR swizzle (R7)
    __shared__ float partl[4][64];

    const int tid = threadIdx.x;
    const int w   = tid >> 6;
    const int l   = tid & 63;
    const int lc  = l & 15;
    const int lk  = l >> 4;

    const u16* w1b = w1fr + w * 8192  + l * 8;
    const u16* w2b = w2fr + w * 16384 + l * 8;

    // glds lane constants (R6, verified)
    const int dl = w * 4 + (l >> 4);
    const int m0 = (l & 15) * 4;

    // loop-invariant: biases folded into acc init, W3/b3 hoisted
    float4 b1q[4];
    #pragma unroll
    for (int mt = 0; mt < 4; ++mt)
        b1q[mt] = *(const float4*)(b1 + 64 * w + 16 * mt + 4 * lk);
    float b2v[4], w3v[4];
    #pragma unroll
    for (int nt = 0; nt < 4; ++nt) {
        const int e = 64 * w + 16 * nt + lc;
        b2v[nt] = b2[e];
        w3v[nt] = W3[e];
    }
    const float b3v = b3[0];

    // ---------- prologue: stage X[b0] ----------
    int b = blockIdx.x;
    {
        const float* Xb = X + (size_t)b * 8192;
        #pragma unroll
        for (int i = 0; i < 8; ++i) {
            const int d = i * 16 + dl;
            const float* src = Xb + d * 64 + (m0 ^ (((d >> 3) & 1) << 4));
            __builtin_amdgcn_global_load_lds(
                (const __attribute__((address_space(1))) void*)src,
                (__attribute__((address_space(3))) void*)(xs + i * 1024 + w * 256 + (l & 63) * 4),
                16, 0, 0);
        }
    }
    __syncthreads();

    #pragma unroll 1
    for (int it = 0; it < ITERS; ++it, b += GRID_P) {
        // ---------- layer 1: D1[c][n] = sum_d W1[d][c] * X[d][n], bias in acc init ----------
        f32x4 acc[4][4];
        #pragma unroll
        for (int mt = 0; mt < 4; ++mt)
            #pragma unroll
            for (int nt = 0; nt < 4; ++nt)
                acc[mt][nt] = (f32x4){b1q[mt].x, b1q[mt].y, b1q[mt].z, b1q[mt].w};

        bf16x8 afrN[4];
        #pragma unroll
        for (int mt = 0; mt < 4; ++mt)
            afrN[mt] = *(const bf16x8*)(w1b + mt * 2048);

        const int px = (lk & 1) << 4;
        #pragma unroll
        for (int ks = 0; ks < 4; ++ks) {
            bf16x8 afr[4], bfr[4];
            #pragma unroll
            for (int mt = 0; mt < 4; ++mt) afr[mt] = afrN[mt];
            if (ks < 3) {
                #pragma unroll
                for (int mt = 0; mt < 4; ++mt)
                    afrN[mt] = *(const bf16x8*)(w1b + (mt * 4 + ks + 1) * 512);
            }
            #pragma unroll
            for (int nt = 0; nt < 4; ++nt) {
                const int col = (16 * nt + lc) ^ px;
                const int rb  = (32 * ks + 8 * lk) * 64 + col;
                float xv[8];
                #pragma unroll
                for (int j = 0; j < 8; ++j) xv[j] = xs[rb + j * 64];
                union { bf16x8 v; u32 d[4]; } fr;
                #pragma unroll
                for (int j = 0; j < 4; ++j) fr.d[j] = pack2bf(xv[2 * j], xv[2 * j + 1]);
                bfr[nt] = fr.v;
            }
            __builtin_amdgcn_s_setprio(1);
            #pragma unroll
            for (int mt = 0; mt < 4; ++mt)
                #pragma unroll
                for (int nt = 0; nt < 4; ++nt)
                    acc[mt][nt] = __builtin_amdgcn_mfma_f32_16x16x32_bf16(afr[mt], bfr[nt], acc[mt][nt], 0, 0, 0);
            __builtin_amdgcn_s_setprio(0);
        }
        __syncthreads();                           // B1: all xs reads done

        // ---------- issue next-batch glds (lands across B2, waited at B4) ----------
        const int bn = b + GRID_P;
        if (bn < NB) {
            const float* Xb = X + (size_t)bn * 8192;
            #pragma unroll
            for (int i = 0; i < 8; ++i) {
                const int d = i * 16 + dl;
                const float* src = Xb + d * 64 + (m0 ^ (((d >> 3) & 1) << 4));
                __builtin_amdgcn_global_load_lds(
                    (const __attribute__((address_space(1))) void*)src,
                    (__attribute__((address_space(3))) void*)(xs + i * 1024 + w * 256 + (l & 63) * 4),
                    16, 0, 0);
            }
        }

        // ---------- epilogue 1: relu, pack -> h1s ----------
        #pragma unroll
        for (int mt = 0; mt < 4; ++mt) {
            const int c0 = 64 * w + 16 * mt + 4 * lk;
            #pragma unroll
            for (int nt = 0; nt < 4; ++nt) {
                const int n = 16 * nt + lc;
                float x0 = fmaxf(acc[mt][nt][0], 0.f);
                float x1 = fmaxf(acc[mt][nt][1], 0.f);
                float x2 = fmaxf(acc[mt][nt][2], 0.f);
                float x3 = fmaxf(acc[mt][nt][3], 0.f);
                const int chunk = (c0 >> 3) ^ lc;
                *(uint2*)(h1s + n * 256 + (chunk << 3) + (c0 & 7)) =
                    make_uint2(pack2bf(x0, x1), pack2bf(x2, x3));
            }
        }

        // B2 raw: LDS-drain only; glds stays in flight across the barrier
        asm volatile("s_waitcnt lgkmcnt(0)" ::: "memory");
        __builtin_amdgcn_s_barrier();
        asm volatile("" ::: "memory");

        // ---------- layer 2: D2[n][e] = sum_c h1[n][c] * W2[c][e], bias in acc init ----------
        f32x4 acc2[4][4];
        #pragma unroll
        for (int mt = 0; mt < 4; ++mt)
            #pragma unroll
            for (int nt = 0; nt < 4; ++nt)
                acc2[mt][nt] = (f32x4){b2v[nt], b2v[nt], b2v[nt], b2v[nt]};

        bf16x8 bfrN[4];
        #pragma unroll
        for (int nt = 0; nt < 4; ++nt)
            bfrN[nt] = *(const bf16x8*)(w2b + nt * 4096);

        #pragma unroll
        for (int ks = 0; ks < 8; ++ks) {
            bf16x8 afr[4], bfr[4];
            #pragma unroll
            for (int nt = 0; nt < 4; ++nt) bfr[nt] = bfrN[nt];
            if (ks < 7) {
                #pragma unroll
                for (int nt = 0; nt < 4; ++nt)
                    bfrN[nt] = *(const bf16x8*)(w2b + (nt * 8 + ks + 1) * 512);
            }
            #pragma unroll
            for (int mt = 0; mt < 4; ++mt)
                afr[mt] = *(const bf16x8*)(h1s + (16 * mt + lc) * 256 + (((4 * ks + lk) ^ lc) << 3));
            __builtin_amdgcn_s_setprio(1);
            #pragma unroll
            for (int mt = 0; mt < 4; ++mt)
                #pragma unroll
                for (int nt = 0; nt < 4; ++nt)
                    acc2[mt][nt] = __builtin_amdgcn_mfma_f32_16x16x32_bf16(afr[mt], bfr[nt], acc2[mt][nt], 0, 0, 0);
            __builtin_amdgcn_s_setprio(0);
        }

        // ---------- layer 3: relu, dot W3, reduce over e ----------
        #pragma unroll
        for (int mt = 0; mt < 4; ++mt) {
            #pragma unroll
            for (int j = 0; j < 4; ++j) {          // row n = 16mt + 4lk + j
                float s = 0.f;
                #pragma unroll
                for (int nt = 0; nt < 4; ++nt)
                    s += fmaxf(acc2[mt][nt][j], 0.f) * w3v[nt];
                s += __shfl_xor(s, 1);
                s += __shfl_xor(s, 2);
                s += __shfl_xor(s, 4);
                s += __shfl_xor(s, 8);
                if (lc == 0) partl[w][16 * mt + 4 * lk + j] = s;
            }
        }

        // B3 raw: partl visible; glds still unwaited
        asm volatile("s_waitcnt lgkmcnt(0)" ::: "memory");
        __builtin_amdgcn_s_barrier();
        asm volatile("" ::: "memory");

        if (tid < 64) {
            float s = partl[0][tid] + partl[1][tid] + partl[2][tid] + partl[3][tid] + b3v;
            out[(size_t)b * 65 + 1 + tid] = s;
        } else if (tid == 64) {
            out[(size_t)b * 65] = 0.f;
        }

        __syncthreads();                           // B4: full drain -> xs[b+512] valid, WAR fences
    }
}

extern "C" void kernel_launch(void* const* d_in, const int* in_sizes, int n_in,
                              void* d_out, int out_size, void* d_ws, size_t ws_size,
                              hipStream_t stream) {
    const float* X  = (const float*)d_in[0];
    const float* W1 = (const float*)d_in[1];
    const float* b1 = (const float*)d_in[2];
    const float* W2 = (const float*)d_in[3];
    const float* b2 = (const float*)d_in[4];
    const float* W3 = (const float*)d_in[5];
    const float* b3 = (const float*)d_in[6];
    float* out = (float*)d_out;

    u16* w1fr = (u16*)d_ws;            // 64 KB
    u16* w2fr = w1fr + 32768;          // 128 KB

    prep_weights<<<384, 256, 0, stream>>>(W1, W2, w1fr, w2fr);
    fused_mlp<<<GRID_P, 256, 0, stream>>>(X, b1, b2, W3, b3, w1fr, w2fr, out);
}